// Round 1
// 18070.969 us; speedup vs baseline: 1.9202x; 1.9202x over previous
//
#include <hip/hip_runtime.h>
#include <cstddef>

#define T_STEPS 4096
#define H_DIM   4096
#define IN_DIM  1024
#define O_DIM   512
#define N_WG    256   // 1 block/CU -- launch shape proven in prior rounds

typedef unsigned long long u64;

__device__ __forceinline__ float sigmoid_f(float v) {
    v = fminf(fmaxf(v, -30.f), 30.f);
    return 1.f / (1.f + __expf(-v));
}
__device__ __forceinline__ float tanh_f(float v) {
    v = fminf(fmaxf(v, -15.f), 15.f);
    float e = __expf(2.f * v);
    return (e - 1.f) / (e + 1.f);
}

// Keep W_rec register rows opaque so the scheduler can't sink/remat the
// global loads into the t-loop (prior rounds: remat = 84 MB/step L2 re-reads).
#define PIN4(v) asm volatile("" : "+v"(v.x), "+v"(v.y), "+v"(v.z), "+v"(v.w))

// fp32 -> packed bf16x2 (round-to-nearest-even), and unpack helpers.
__device__ __forceinline__ unsigned pack_bf2(float a, float b) {
    unsigned ua = __float_as_uint(a), ub = __float_as_uint(b);
    ua = (ua + 0x7fffu + ((ua >> 16) & 1u)) >> 16;
    ub = (ub + 0x7fffu + ((ub >> 16) & 1u)) & 0xffff0000u;
    return ua | ub;
}
__device__ __forceinline__ float bf_lo(unsigned u) { return __uint_as_float(u << 16); }
__device__ __forceinline__ float bf_hi(unsigned u) { return __uint_as_float(u & 0xffff0000u); }

// R8: DATA-GENERATION FUSED BARRIER. R7 was still ~4 serialized L3 round
// trips/step (h-store drain -> flag store -> 65K-poller flag discovery ->
// h reload). Now each h element is a 64-bit (gen<<32 | value) word stored
// with one relaxed agent-scope atomic; consumers poll the DATA. The poll IS
// the staging load: flags array gone, producer drain gone, reload gone.
// Safety: double-buffer parity means gen in buf[t&1] takes values t, t+2, ...
// and a WG can only publish gen t+2 after every WG finished staging gen t+1,
// which requires every WG to have fully staged gen t first => '== t' polling
// can never miss or skip a generation.
// Also: W_in.x, W_out.h, x staging, y stores moved into the slack after the
// h' store; all 16 W_rec rows now VGPR-resident (w_lds stream eliminated).
__global__ __launch_bounds__(512, 2) void snn_persistent(
    const float* __restrict__ x, const float* __restrict__ Win,
    const float* __restrict__ Wrec, const float* __restrict__ Wout,
    const float* __restrict__ gbias, float* __restrict__ y,
    u64* __restrict__ hbuf)
{
    __shared__ __attribute__((aligned(16))) float h_lds[H_DIM];   // 16 KB
    __shared__ __attribute__((aligned(16))) float x_lds[IN_DIM];  // 4 KB
    __shared__ float osc[8][2];

    const int tid = threadIdx.x;
    const int w   = tid >> 6;     // wave 0..7
    const int l   = tid & 63;     // lane
    const int wg  = blockIdx.x;   // 0..255

    const int rowA  = wg * 16 + w;      // both W_rec rows register-resident now
    const int rowB  = rowA + 8;
    const int orow0 = wg * 2;
    const int orow1 = orow0 + 1;

    // ---- one-time: 32 register-resident W_rec row-slices (128 VGPRs) ----
    const float4* pa = (const float4*)Wrec + (size_t)rowA * (H_DIM / 4) + l;
    const float4* pb = (const float4*)Wrec + (size_t)rowB * (H_DIM / 4) + l;
#define WRL(k) float4 wa##k = pa[(k) * 64]; PIN4(wa##k); \
               float4 wb##k = pb[(k) * 64]; PIN4(wb##k);
    WRL(0) WRL(1) WRL(2) WRL(3) WRL(4) WRL(5) WRL(6) WRL(7)
    WRL(8) WRL(9) WRL(10) WRL(11) WRL(12) WRL(13) WRL(14) WRL(15)
#undef WRL

    const float4* pia = (const float4*)Win + (size_t)rowA * (IN_DIM / 4) + l;
    const float4* pib = (const float4*)Win + (size_t)rowB * (IN_DIM / 4) + l;
    unsigned wiA[8], wiB[8];
    #pragma unroll
    for (int k = 0; k < 4; ++k) {
        float4 va = pia[k * 64], vb = pib[k * 64];
        wiA[2 * k]     = pack_bf2(va.x, va.y);
        wiA[2 * k + 1] = pack_bf2(va.z, va.w);
        wiB[2 * k]     = pack_bf2(vb.x, vb.y);
        wiB[2 * k + 1] = pack_bf2(vb.z, vb.w);
    }

    const float* po0 = Wout + (size_t)orow0 * H_DIM + tid;
    const float* po1 = Wout + (size_t)orow1 * H_DIM + tid;
    unsigned woP0[4], woP1[4];
    #pragma unroll
    for (int j = 0; j < 4; ++j) {
        woP0[j] = pack_bf2(po0[1024 * j], po0[1024 * j + 512]);
        woP1[j] = pack_bf2(po1[1024 * j], po1[1024 * j + 512]);
    }

    const float gbA  = gbias[rowA];
    const float gbB  = gbias[rowB];
    const float leak = 0.1f;

    u64* b0 = hbuf;          // holds h_t for even t (memset 0 => gen 0, h0 = 0)
    u64* b1 = hbuf + H_DIM;  // holds h_t for odd t

    float iA, iB;            // input currents, computed one step ahead (slack)
#define COMPUTE_I() do { iA = 0.f; iB = 0.f;                                    \
        const float4* x4_ = (const float4*)x_lds;                               \
        _Pragma("unroll")                                                       \
        for (int k = 0; k < 4; ++k) {                                           \
            float4 xv = x4_[k * 64 + l];                                        \
            unsigned a0 = wiA[2 * k], a1 = wiA[2 * k + 1];                      \
            unsigned c0 = wiB[2 * k], c1 = wiB[2 * k + 1];                      \
            iA = fmaf(bf_lo(a0), xv.x, fmaf(bf_hi(a0), xv.y,                    \
                 fmaf(bf_lo(a1), xv.z, fmaf(bf_hi(a1), xv.w, iA))));            \
            iB = fmaf(bf_lo(c0), xv.x, fmaf(bf_hi(c0), xv.y,                    \
                 fmaf(bf_lo(c1), xv.z, fmaf(bf_hi(c1), xv.w, iB))));            \
        }                                                                       \
        _Pragma("unroll")                                                       \
        for (int off = 32; off; off >>= 1) {                                    \
            iA += __shfl_xor(iA, off); iB += __shfl_xor(iB, off);               \
        } } while (0)

    float vals[8];           // this thread's 8 freshly-polled h values
#define POLL_STAGE(SRC, GEN) do { unsigned pend = 0xffu;                        \
        while (pend) {                                                          \
            _Pragma("unroll")                                                   \
            for (int k = 0; k < 8; ++k) if (pend & (1u << k)) {                 \
                u64 v_ = __hip_atomic_load(&(SRC)[tid + (k << 9)],              \
                        __ATOMIC_RELAXED, __HIP_MEMORY_SCOPE_AGENT);            \
                if ((unsigned)(v_ >> 32) == (GEN)) {                            \
                    vals[k] = __uint_as_float((unsigned)v_);                    \
                    pend &= ~(1u << k);                                         \
                }                                                               \
            }                                                                   \
            if (pend) __builtin_amdgcn_s_sleep(1);  /* ~64cy backoff */         \
        } } while (0)

    // W_out partials straight from vals[] registers (slot k = tid + 512k, so
    // vals[2j]/vals[2j+1] are exactly h[tid+1024j]/h[tid+1024j+512]).
#define WOUT_OSC() do { float p0 = 0.f, p1 = 0.f;                               \
        _Pragma("unroll")                                                       \
        for (int j = 0; j < 4; ++j) {                                           \
            p0 = fmaf(bf_lo(woP0[j]), vals[2 * j],                              \
                 fmaf(bf_hi(woP0[j]), vals[2 * j + 1], p0));                    \
            p1 = fmaf(bf_lo(woP1[j]), vals[2 * j],                              \
                 fmaf(bf_hi(woP1[j]), vals[2 * j + 1], p1));                    \
        }                                                                       \
        _Pragma("unroll")                                                       \
        for (int off = 32; off; off >>= 1) {                                    \
            p0 += __shfl_xor(p0, off); p1 += __shfl_xor(p1, off);               \
        }                                                                       \
        if (l == 0) { osc[w][0] = p0; osc[w][1] = p1; } } while (0)

    // ---- prologue: x_0 staged, input currents for t=0 precomputed ----
    if (tid < 256) ((float4*)x_lds)[tid] = ((const float4*)x)[tid];
    __syncthreads();
    COMPUTE_I();

    #pragma unroll 1
    for (int t = 0; t < T_STEPS; ++t) {
        const u64* src = (t & 1) ? b1 : b0;
        u64*       dst = (t & 1) ? b0 : b1;

        // ---- the poll IS the grid barrier AND the h staging load ----
        POLL_STAGE(src, (unsigned)t);
        #pragma unroll
        for (int k = 0; k < 8; ++k) h_lds[tid + (k << 9)] = vals[k];
        __syncthreads();                          // S1: h_t fully staged

        // ---- CRITICAL PATH: W_rec . h -> reduce -> nonlinearity -> publish
        float4 a = make_float4(0.f, 0.f, 0.f, 0.f);
        float4 b = make_float4(0.f, 0.f, 0.f, 0.f);
        {
            const float4* h4 = (const float4*)h_lds;
#define WRF(k) { float4 hv = h4[(k) * 64 + l];                                  \
                 a.x = fmaf(wa##k.x, hv.x, a.x); a.y = fmaf(wa##k.y, hv.y, a.y);\
                 a.z = fmaf(wa##k.z, hv.z, a.z); a.w = fmaf(wa##k.w, hv.w, a.w);\
                 b.x = fmaf(wb##k.x, hv.x, b.x); b.y = fmaf(wb##k.y, hv.y, b.y);\
                 b.z = fmaf(wb##k.z, hv.z, b.z); b.w = fmaf(wb##k.w, hv.w, b.w); }
            WRF(0) WRF(1) WRF(2) WRF(3) WRF(4) WRF(5) WRF(6) WRF(7)
            WRF(8) WRF(9) WRF(10) WRF(11) WRF(12) WRF(13) WRF(14) WRF(15)
#undef WRF
        }
        float rA = (a.x + a.y) + (a.z + a.w);
        float rB = (b.x + b.y) + (b.z + b.w);
        #pragma unroll
        for (int off = 32; off; off >>= 1) {
            rA += __shfl_xor(rA, off);
            rB += __shfl_xor(rB, off);
        }
        if (l == 0) {                             // lane0/lane1 in parallel
            float gA = sigmoid_f(gbA + rA);
            float zA = tanh_f(fmaf(gA, rA, iA));
            float hA = h_lds[rowA];
            float hn = fmaf(leak, zA - hA, hA);
            __hip_atomic_store(&dst[rowA],
                ((u64)(unsigned)(t + 1) << 32) | (u64)__float_as_uint(hn),
                __ATOMIC_RELAXED, __HIP_MEMORY_SCOPE_AGENT);
        } else if (l == 1) {
            float gB = sigmoid_f(gbB + rB);
            float zB = tanh_f(fmaf(gB, rB, iB));
            float hB = h_lds[rowB];
            float hn = fmaf(leak, zB - hB, hB);
            __hip_atomic_store(&dst[rowB],
                ((u64)(unsigned)(t + 1) << 32) | (u64)__float_as_uint(hn),
                __ATOMIC_RELAXED, __HIP_MEMORY_SCOPE_AGENT);
        }

        // ---- SLACK (h' already in flight): x, W_out, y, next W_in ----
        if (t + 1 < T_STEPS && tid < 256)
            ((float4*)x_lds)[tid] =
                ((const float4*)(x + (size_t)(t + 1) * IN_DIM))[tid];
        if (t >= 1) WOUT_OSC();                   // y_{t-1} partials from vals
        __syncthreads();                          // S2: osc + x_lds ready
        if (t >= 1 && tid == 0) {
            float s0 = 0.f, s1 = 0.f;
            #pragma unroll
            for (int q = 0; q < 8; ++q) { s0 += osc[q][0]; s1 += osc[q][1]; }
            y[(size_t)(t - 1) * O_DIM + orow0] = s0;
            y[(size_t)(t - 1) * O_DIM + orow1] = s1;
        }
        if (t + 1 < T_STEPS) COMPUTE_I();         // input currents for t+1
    }

    // ---- epilogue: y[T-1] = W_out . h_T (gen T sits in b0, T even) ----
    POLL_STAGE(b0, (unsigned)T_STEPS);
    __syncthreads();   // ensure tid0 finished reading osc for y[T-2]
    WOUT_OSC();
    __syncthreads();
    if (tid == 0) {
        float s0 = 0.f, s1 = 0.f;
        #pragma unroll
        for (int q = 0; q < 8; ++q) { s0 += osc[q][0]; s1 += osc[q][1]; }
        y[(size_t)(T_STEPS - 1) * O_DIM + orow0] = s0;
        y[(size_t)(T_STEPS - 1) * O_DIM + orow1] = s1;
    }
}

extern "C" void kernel_launch(void* const* d_in, const int* in_sizes, int n_in,
                              void* d_out, int out_size, void* d_ws, size_t ws_size,
                              hipStream_t stream) {
    const float* x     = (const float*)d_in[0];
    const float* Win   = (const float*)d_in[1];
    const float* Wrec  = (const float*)d_in[2];
    const float* Wout  = (const float*)d_in[3];
    const float* gbias = (const float*)d_in[4];
    float* y = (float*)d_out;

    u64* hbuf = (u64*)d_ws;  // 2 x 4096 x (gen<<32 | h-bits) = 64 KB

    // ws is re-poisoned before every replay: zero => h0 = 0 with gen 0.
    hipMemsetAsync(d_ws, 0, 2 * H_DIM * sizeof(u64), stream);

    void* args[] = { (void*)&x, (void*)&Win, (void*)&Wrec, (void*)&Wout,
                     (void*)&gbias, (void*)&y, (void*)&hbuf };
    hipLaunchCooperativeKernel((const void*)snn_persistent, dim3(N_WG), dim3(512),
                               args, 0, stream);
}